// Round 5
// baseline (384.259 us; speedup 1.0000x reference)
//
#include <hip/hip_runtime.h>
#include <math.h>

// CapsNet dynamic routing via bf16 MFMA with hi/lo split (error ~2^-17).
//   x: [512,1152,8] f32, w: [10,1152,16,8] f32, out: [512,10,16] f32
// p1: s0 = GEMM over (n,k) with K=32 packing (4n x 8k), 3-MFMA split, AGPR accum.
// p2: per-n MFMA with split packed into K: A=[x_hi|x_lo|x_hi|0], B=[w_hi|w_hi|w_lo|0];
//     logits via in-wave shfl d-reduce; softmax in-register; NO per-n barriers.
// Partials -> ws slab P[ns][512][160]; reduce_squash sums + squashes.

#define BB   512
#define NN1  1152
#define CC2  10
#define DD2  16
#define CD   160
#define WCN  (NN1*DD2*8)   // 147456 floats per c in w
#define XB   (NN1*8)       // 9216 floats per b in x

typedef __attribute__((ext_vector_type(8))) short bf16x8;
typedef __attribute__((ext_vector_type(4))) float f32x4;

__device__ __forceinline__ unsigned short f2bf_rne(float f) {
    unsigned u = __builtin_bit_cast(unsigned, f);
    u += 0x7FFFu + ((u >> 16) & 1u);
    return (unsigned short)(u >> 16);
}
__device__ __forceinline__ float bf2f(unsigned short s) {
    unsigned u = ((unsigned)s) << 16;
    return __builtin_bit_cast(float, u);
}

// ---------------- P1: partial raw s0 over this block's n-slice ----------------
template<int NS>
__global__ __launch_bounds__(256) void caps_p1(
    const float* __restrict__ x, const float* __restrict__ w, float* __restrict__ P)
{
    constexpr int NT = NN1 / NS;     // multiple of 4
    constexpr int TILES = NT / 4;
    __shared__ __align__(16) unsigned short whi[5120], wlo[5120];   // [c][nq][d][k]
    __shared__ __align__(16) unsigned short xhi[2048], xlo[2048];   // [nq][b][k]

    const int ns = blockIdx.x, bc = blockIdx.y;
    const int tid = threadIdx.x;
    const int l = tid & 63, wv = tid >> 6;
    const int lo4 = l & 15, kblk = l >> 4;

    f32x4 acc[10];
#pragma unroll
    for (int c = 0; c < 10; ++c) acc[c] = (f32x4){0.f, 0.f, 0.f, 0.f};

    for (int t4 = 0; t4 < TILES; ++t4) {
        const int n0 = ns * NT + t4 * 4;
        __syncthreads();               // WAR on LDS
#pragma unroll
        for (int e = 0; e < 20; ++e) { // w: 10c x 4n x 128 = 5120 f32
            int idx = tid + e * 256;
            int c = idx >> 9, rem = idx & 511;
            float f = w[c * WCN + n0 * 128 + rem];
            unsigned short h = f2bf_rne(f);
            whi[idx] = h;
            wlo[idx] = f2bf_rne(f - bf2f(h));
        }
#pragma unroll
        for (int e = 0; e < 8; ++e) {  // x: 64b x 4n x 8k = 2048 f32
            int idx = tid + e * 256;
            int b_l = idx >> 5, rem = idx & 31;
            int nq = rem >> 3, k = rem & 7;
            float f = x[(bc * 64 + b_l) * XB + (n0 + nq) * 8 + k];
            unsigned short h = f2bf_rne(f);
            int li = (nq * 64 + b_l) * 8 + k;
            xhi[li] = h;
            xlo[li] = f2bf_rne(f - bf2f(h));
        }
        __syncthreads();               // RAW

        // A[row=b (lane&15), k=(lane>>4)*8+e]: k-blocks = the 4 n's
        int ia = (kblk * 64 + wv * 16 + lo4) * 8;
        bf16x8 ahi = *(const bf16x8*)(xhi + ia);
        bf16x8 alo = *(const bf16x8*)(xlo + ia);
#pragma unroll
        for (int c = 0; c < 10; ++c) {
            int ib = (c * 4 + kblk) * 128 + lo4 * 8;   // B[k-blk=n, col=d]
            bf16x8 bhi = *(const bf16x8*)(whi + ib);
            bf16x8 blo = *(const bf16x8*)(wlo + ib);
            acc[c] = __builtin_amdgcn_mfma_f32_16x16x32_bf16(ahi, bhi, acc[c], 0, 0, 0);
            acc[c] = __builtin_amdgcn_mfma_f32_16x16x32_bf16(alo, bhi, acc[c], 0, 0, 0);
            acc[c] = __builtin_amdgcn_mfma_f32_16x16x32_bf16(ahi, blo, acc[c], 0, 0, 0);
        }
    }

    // C layout: col=lane&15 (=d), row=(lane>>4)*4+reg (=b within 16-group)
    float* base = P + (size_t)ns * BB * CD;
#pragma unroll
    for (int c = 0; c < 10; ++c)
#pragma unroll
        for (int r = 0; r < 4; ++r) {
            int b = bc * 64 + wv * 16 + kblk * 4 + r;
            base[(size_t)b * CD + c * 16 + lo4] = acc[c][r];
        }
}

// ------- reduce over ns + squash(alpha*S), element-per-thread, shfl norm -------
__global__ void reduce_squash(const float* __restrict__ P, float* __restrict__ out,
                              int nsplit, float asq)
{
    int t = blockIdx.x * 256 + threadIdx.x;   // element (b,c,d); 16-lane groups = one (b,c)
    if (t >= BB * CD) return;
    float s = 0.f;
    const float* p = P + t;
    for (int ns = 0; ns < nsplit; ++ns, p += (size_t)BB * CD) s += *p;
    float sq = s * s;
#pragma unroll
    for (int m = 1; m < 16; m <<= 1) sq += __shfl_xor(sq, m, 64);   // sum over d
    float qq = asq * sq;                          // |alpha*S|^2
    float sc = qq / (1.f + qq) / sqrtf(sq);       // out = sc * S (alpha folded)
    out[t] = s * sc;
}

// ---------------- P2: per-n MFMA + in-wave softmax + weighted sum ----------------
template<int NS>
__global__ __launch_bounds__(256) void caps_p2(
    const float* __restrict__ x, const float* __restrict__ w,
    const float* __restrict__ o0, float* __restrict__ P)
{
    constexpr int NT = NN1 / NS;
    constexpr int TILES = NT / 4;
    __shared__ __align__(16) unsigned short whi[5120], wlo[5120];
    __shared__ __align__(16) unsigned short xhi[2048], xlo[2048];
    __shared__ __align__(16) unsigned short zpad[8];

    const int ns = blockIdx.x, bc = blockIdx.y;
    const int tid = threadIdx.x;
    const int l = tid & 63, wv = tid >> 6;
    const int lo4 = l & 15, kblk = l >> 4;
    if (tid < 8) zpad[tid] = 0;

    // o0 resident: o0r[c][r] for C-rows b = bc*64 + wv*16 + kblk*4 + r, col d = lo4
    float o0r[10][4];
#pragma unroll
    for (int c = 0; c < 10; ++c)
#pragma unroll
        for (int r = 0; r < 4; ++r)
            o0r[c][r] = o0[(size_t)(bc * 64 + wv * 16 + kblk * 4 + r) * CD + c * 16 + lo4];

    f32x4 s1[10];
#pragma unroll
    for (int c = 0; c < 10; ++c) s1[c] = (f32x4){0.f, 0.f, 0.f, 0.f};

    for (int t4 = 0; t4 < TILES; ++t4) {
        const int n0 = ns * NT + t4 * 4;
        __syncthreads();
#pragma unroll
        for (int e = 0; e < 20; ++e) {
            int idx = tid + e * 256;
            int c = idx >> 9, rem = idx & 511;
            float f = w[c * WCN + n0 * 128 + rem];
            unsigned short h = f2bf_rne(f);
            whi[idx] = h;
            wlo[idx] = f2bf_rne(f - bf2f(h));
        }
#pragma unroll
        for (int e = 0; e < 8; ++e) {
            int idx = tid + e * 256;
            int b_l = idx >> 5, rem = idx & 31;
            int nq = rem >> 3, k = rem & 7;
            float f = x[(bc * 64 + b_l) * XB + (n0 + nq) * 8 + k];
            unsigned short h = f2bf_rne(f);
            int li = (nq * 64 + b_l) * 8 + k;
            xhi[li] = h;
            xlo[li] = f2bf_rne(f - bf2f(h));
        }
        __syncthreads();

#pragma unroll
        for (int nt = 0; nt < 4; ++nt) {
            // A k-blocks: [x_hi | x_lo | x_hi | 0]  (one n)
            int ia = (nt * 64 + wv * 16 + lo4) * 8;
            const unsigned short* pa = (kblk == 1) ? (xlo + ia) : (xhi + ia);
            if (kblk == 3) pa = zpad;
            bf16x8 av = *(const bf16x8*)pa;

            f32x4 xh[10];
#pragma unroll
            for (int c = 0; c < 10; ++c) {
                // B k-blocks: [w_hi | w_hi | w_lo | 0]
                int ib = (c * 4 + nt) * 128 + lo4 * 8;
                const unsigned short* pb = (kblk < 2) ? (whi + ib) : (wlo + ib);
                if (kblk == 3) pb = zpad;
                bf16x8 bv = *(const bf16x8*)pb;
                xh[c] = __builtin_amdgcn_mfma_f32_16x16x32_bf16(
                    av, bv, (f32x4){0.f, 0.f, 0.f, 0.f}, 0, 0, 0);
            }

            // logits: L[b(r), c] = sum_d xh*o0 ; d = lo4 spans lane bits 0..3
            float lp[10][4];
#pragma unroll
            for (int c = 0; c < 10; ++c)
#pragma unroll
                for (int r = 0; r < 4; ++r) lp[c][r] = xh[c][r] * o0r[c][r];
#pragma unroll
            for (int m = 1; m < 16; m <<= 1)
#pragma unroll
                for (int c = 0; c < 10; ++c)
#pragma unroll
                    for (int r = 0; r < 4; ++r)
                        lp[c][r] += __shfl_xor(lp[c][r], m, 64);

            // softmax over c (per row r), then weighted accumulation
#pragma unroll
            for (int r = 0; r < 4; ++r) {
                float mx = lp[0][r];
#pragma unroll
                for (int c = 1; c < 10; ++c) mx = fmaxf(mx, lp[c][r]);
                float e[10], den = 0.f;
#pragma unroll
                for (int c = 0; c < 10; ++c) { e[c] = __expf(lp[c][r] - mx); den += e[c]; }
                float inv = 1.f / den;
#pragma unroll
                for (int c = 0; c < 10; ++c) s1[c][r] += e[c] * inv * xh[c][r];
            }
        }
    }

    float* base = P + (size_t)ns * BB * CD;
#pragma unroll
    for (int c = 0; c < 10; ++c)
#pragma unroll
        for (int r = 0; r < 4; ++r) {
            int b = bc * 64 + wv * 16 + kblk * 4 + r;
            base[(size_t)b * CD + c * 16 + lo4] = s1[c][r];
        }
}

extern "C" void kernel_launch(void* const* d_in, const int* in_sizes, int n_in,
                              void* d_out, int out_size, void* d_ws, size_t ws_size,
                              hipStream_t stream)
{
    (void)in_sizes; (void)n_in; (void)out_size;
    const float* x = (const float*)d_in[0];
    const float* w = (const float*)d_in[1];
    float* out = (float*)d_out;
    float* ws  = (float*)d_ws;

#define LAUNCH_NS(NSV)                                                               \
    do {                                                                             \
        float* P  = ws;                                                              \
        float* o0 = ws + (size_t)(NSV) * BB * CD;                                    \
        caps_p1<NSV><<<dim3(NSV, 8), 256, 0, stream>>>(x, w, P);                     \
        reduce_squash<<<(BB * CD + 255) / 256, 256, 0, stream>>>(P, o0, NSV, 0.01f); \
        caps_p2<NSV><<<dim3(NSV, 8), 256, 0, stream>>>(x, w, o0, P);                 \
        reduce_squash<<<(BB * CD + 255) / 256, 256, 0, stream>>>(P, out, NSV, 1.0f); \
    } while (0)

    const size_t slab = (size_t)BB * CD * sizeof(float);   // 327680 B
    if      (ws_size >= slab * 73) LAUNCH_NS(72);   // NT=16
    else if (ws_size >= slab * 37) LAUNCH_NS(36);   // NT=32
    else if (ws_size >= slab * 19) LAUNCH_NS(18);   // NT=64
    else                           LAUNCH_NS(9);    // NT=128
#undef LAUNCH_NS
}

// Round 7
// 119.842 us; speedup vs baseline: 3.2064x; 3.2064x over previous
//
#include <hip/hip_runtime.h>
#include <math.h>

// CapsNet dynamic routing, all-MFMA (16x16x32 only), hi/lo split packed into K.
//   x: [512,1152,8] f32, w: [10,1152,16,8] f32, out: [512,10,16] f32
// p0:  w -> bf16 hi/lo, natural [c][n][d][k] and transposed [c][n][k][d] (once).
// p1:  s0 partials via mfma(K = 4n x 8k), 3-term hi/lo split, VGPR accum.
// p2:  per n-pair: logits via mfma(A=[wT_hi|wT_lo] K=2*d, B=[o0h|o0h]) + 4 FMA + 1 shfl;
//      softmax in-lane; s1 via per-n mfma(A=[w_hi|w_lo|w_hi|*], B=[x_hi|x_hi|x_lo|0]),
//      scaled after by c1 (1 shfl/c). No LDS/barriers/atomics in hot loops.
// Partials -> P[ns][b][160]; reduce_squash sums + squashes.

#define BB   512
#define NN1  1152
#define CD   160
#define XB   (NN1*8)           // 9216
#define WELEM (10*NN1*16*8)    // 1474560

typedef __attribute__((ext_vector_type(8))) short bf16x8;
typedef __attribute__((ext_vector_type(4))) float f32x4;

#define MFMA32(a, b, c) __builtin_amdgcn_mfma_f32_16x16x32_bf16(a, b, c, 0, 0, 0)
#define ZERO4 ((f32x4){0.f, 0.f, 0.f, 0.f})

__device__ __forceinline__ short f2bf(float f) {
    unsigned u = __builtin_bit_cast(unsigned, f);
    u += 0x7FFFu + ((u >> 16) & 1u);
    return (short)(u >> 16);
}
__device__ __forceinline__ float bf2f(short s) {
    unsigned u = ((unsigned)(unsigned short)s) << 16;
    return __builtin_bit_cast(float, u);
}
__device__ __forceinline__ bf16x8 cvt_hi8(f32x4 a, f32x4 b) {
    bf16x8 r;
#pragma unroll
    for (int i = 0; i < 4; ++i) { r[i] = f2bf(a[i]); r[4 + i] = f2bf(b[i]); }
    return r;
}
__device__ __forceinline__ void cvt_hilo8(f32x4 a, f32x4 b, bf16x8& h, bf16x8& l) {
#pragma unroll
    for (int i = 0; i < 4; ++i) {
        short t = f2bf(a[i]); h[i] = t; l[i] = f2bf(a[i] - bf2f(t));
        t = f2bf(b[i]); h[4 + i] = t; l[4 + i] = f2bf(b[i] - bf2f(t));
    }
}

// ---------------- p0a: w -> wnat hi/lo (coalesced) ----------------
__global__ void p0a(const float* __restrict__ w, short* __restrict__ wh, short* __restrict__ wl)
{
    int i = blockIdx.x * 256 + threadIdx.x;      // 5760*256 == WELEM
    float f = w[i];
    short h = f2bf(f);
    wh[i] = h;
    wl[i] = f2bf(f - bf2f(h));
}
// ---------------- p0b: w -> wT hi/lo, [c][n][k][d] ----------------
__global__ void p0b(const float* __restrict__ w, short* __restrict__ th, short* __restrict__ tl)
{
    int i = blockIdx.x * 256 + threadIdx.x;
    int d = i & 15, k = (i >> 4) & 7, row = i >> 7;   // row = c*1152+n
    float f = w[row * 128 + d * 8 + k];
    short h = f2bf(f);
    th[i] = h;
    tl[i] = f2bf(f - bf2f(h));
}

// ---------------- p1: s0 partials, mfma over (4n x 8k) ----------------
template<int NS>
__global__ __launch_bounds__(256, 4) void caps_p1(
    const float* __restrict__ x, const short* __restrict__ wnh, const short* __restrict__ wnl,
    float* __restrict__ P)
{
    constexpr int NT = NN1 / NS;
    static_assert(NT % 4 == 0, "quads");
    __shared__ float red[2][2560];

    const int ns = blockIdx.x, bt = blockIdx.y;
    const int tid = threadIdx.x, lane = tid & 63, wv = tid >> 6;
    const int lo = lane & 15, g = lane >> 4;
    const int btile = bt * 16;

    f32x4 acc[10];
#pragma unroll
    for (int c = 0; c < 10; ++c) acc[c] = ZERO4;

    for (int q = wv; q < NT / 4; q += 4) {
        const int n0 = ns * NT + q * 4;
        const float* px = x + (size_t)(btile + lo) * XB + (size_t)(n0 + g) * 8;
        f32x4 x0 = *(const f32x4*)px;
        f32x4 x1 = *(const f32x4*)(px + 4);
        bf16x8 ah, al;
        cvt_hilo8(x0, x1, ah, al);
#pragma unroll
        for (int c = 0; c < 10; ++c) {
            size_t off = (((size_t)c * NN1 + n0 + g) * 16 + lo) * 8;
            bf16x8 bh = *(const bf16x8*)(wnh + off);
            bf16x8 bl = *(const bf16x8*)(wnl + off);
            acc[c] = MFMA32(ah, bh, acc[c]);
            acc[c] = MFMA32(al, bh, acc[c]);
            acc[c] = MFMA32(ah, bl, acc[c]);
        }
    }

    // 4-wave reduce; C layout: col=lo=d, row=g*4+e=b-local
    if (wv == 1 || wv == 3) {
        float* s = red[wv >> 1];
#pragma unroll
        for (int c = 0; c < 10; ++c)
#pragma unroll
            for (int e = 0; e < 4; ++e) s[c * 256 + (g * 4 + e) * 16 + lo] = acc[c][e];
    }
    __syncthreads();
    if (wv == 0) {
#pragma unroll
        for (int c = 0; c < 10; ++c)
#pragma unroll
            for (int e = 0; e < 4; ++e) acc[c][e] += red[0][c * 256 + (g * 4 + e) * 16 + lo];
    } else if (wv == 2) {
#pragma unroll
        for (int c = 0; c < 10; ++c)
#pragma unroll
            for (int e = 0; e < 4; ++e) {
                int idx = c * 256 + (g * 4 + e) * 16 + lo;
                red[1][idx] += acc[c][e];
            }
    }
    __syncthreads();
    if (wv == 0) {
        float* dst = P + (size_t)ns * BB * CD;
#pragma unroll
        for (int c = 0; c < 10; ++c)
#pragma unroll
            for (int e = 0; e < 4; ++e)
                dst[(size_t)(btile + g * 4 + e) * CD + c * 16 + lo] =
                    acc[c][e] + red[1][c * 256 + (g * 4 + e) * 16 + lo];
    }
}

// ------- reduce over ns + squash(alpha*S) -------
__global__ void reduce_squash(const float* __restrict__ P, float* __restrict__ out,
                              int nsplit, float asq)
{
    int t = blockIdx.x * 256 + threadIdx.x;      // 320*256 == 81920
    float s = 0.f;
    const float* p = P + t;
    for (int ns = 0; ns < nsplit; ++ns, p += (size_t)BB * CD) s += *p;
    float sq = s * s;
#pragma unroll
    for (int m = 1; m < 16; m <<= 1) sq += __shfl_xor(sq, m, 64);
    float qq = asq * sq;
    float sc = qq / (1.f + qq) / sqrtf(sq);
    out[t] = s * sc;
}

// ---------------- p2: R-GEMM logits + in-lane softmax + scaled s1-GEMM ----------------
template<int NS>
__global__ __launch_bounds__(256, 3) void caps_p2(
    const float* __restrict__ x,
    const short* __restrict__ wnh, const short* __restrict__ wnl,
    const short* __restrict__ wth, const short* __restrict__ wtl,
    const float* __restrict__ o0, float* __restrict__ P)
{
    constexpr int NT = NN1 / NS;
    static_assert(NT % 4 == 0, "pairs");
    __shared__ float red[2][2560];

    const int ns = blockIdx.x, bt = blockIdx.y;
    const int tid = threadIdx.x, lane = tid & 63, wv = tid >> 6;
    const int lo = lane & 15, g = lane >> 4;
    const int btile = bt * 16;
    const int b = btile + lo;
    const int ghalf = g & 1, gtop = g >> 1;
    const int n2r = lo >> 3, kr = lo & 7;

    const short* tsel = (g < 2) ? wth : wtl;     // R-GEMM A: hi for g<2, lo for g>=2
    const short* wsel = ghalf ? wnl : wnh;       // s1 A: hi,lo,hi,(junk: B zeroes blk3)

    // R-GEMM B: o0_hi[b, (g&1)*8 + 0..7] per c
    bf16x8 o0B[10];
    {
        const float* po = o0 + (size_t)b * CD + ghalf * 8;
#pragma unroll
        for (int c = 0; c < 10; ++c)
            o0B[c] = cvt_hi8(*(const f32x4*)(po + c * 16), *(const f32x4*)(po + c * 16 + 4));
    }

    f32x4 acc[10];
#pragma unroll
    for (int c = 0; c < 10; ++c) acc[c] = ZERO4;

    const bf16x8 z8 = {0, 0, 0, 0, 0, 0, 0, 0};

    for (int p = wv; p < NT / 2; p += 4) {
        const int n0 = ns * NT + p * 2;
        const float* px = x + (size_t)b * XB + (size_t)n0 * 8;
        f32x4 x0a = *(const f32x4*)px,       x0b = *(const f32x4*)(px + 4);
        f32x4 x1a = *(const f32x4*)(px + 8), x1b = *(const f32x4*)(px + 12);

        bf16x8 xh0, xl0, xh1, xl1;
        cvt_hilo8(x0a, x0b, xh0, xl0);
        cvt_hilo8(x1a, x1b, xh1, xl1);

        // s1 B-fragments: [x_hi | x_hi | x_lo | 0] along K
        bf16x8 Bx0, Bx1;
        if (g == 3)      { Bx0 = z8;  Bx1 = z8;  }
        else if (g == 2) { Bx0 = xl0; Bx1 = xl1; }
        else             { Bx0 = xh0; Bx1 = xh1; }

        // x slice for logit dot: x[b, n0+gtop, (g&1)*4 + e]
        f32x4 xq = x0a;
        if (!gtop &&  ghalf) xq = x0b;
        if ( gtop && !ghalf) xq = x1a;
        if ( gtop &&  ghalf) xq = x1b;

        // ---- pass 1: logits ----
        float L[10];
#pragma unroll
        for (int c = 0; c < 10; ++c) {
            const short* atp = tsel + (((size_t)c * NN1 + n0 + n2r) * 8 + kr) * 16 + ghalf * 8;
            bf16x8 At = *(const bf16x8*)atp;
            f32x4 r = MFMA32(At, o0B[c], ZERO4);
            float lp = r[0] * xq[0] + r[1] * xq[1] + r[2] * xq[2] + r[3] * xq[3];
            L[c] = lp + __shfl_xor(lp, 16, 64);
        }
        // ---- softmax in-lane (lane owns (b, n0+gtop)) ----
        float mx = L[0];
#pragma unroll
        for (int c = 1; c < 10; ++c) mx = fmaxf(mx, L[c]);
        float den = 0.f;
#pragma unroll
        for (int c = 0; c < 10; ++c) { L[c] = __expf(L[c] - mx); den += L[c]; }
        float inv = 1.f / den;

        // ---- pass 2: s1 += c1 * (w . x) per n ----
#pragma unroll
        for (int c = 0; c < 10; ++c) {
            float c1own = L[c] * inv;
            float c1oth = __shfl_xor(c1own, 32, 64);
            float c1n0 = gtop ? c1oth : c1own;
            float c1n1 = gtop ? c1own : c1oth;
            const short* ap = wsel + (((size_t)c * NN1 + n0) * 16 + lo) * 8;
            bf16x8 A0 = *(const bf16x8*)ap;
            bf16x8 A1 = *(const bf16x8*)(ap + 128);
            f32x4 y0 = MFMA32(A0, Bx0, ZERO4);
            f32x4 y1 = MFMA32(A1, Bx1, ZERO4);
#pragma unroll
            for (int e = 0; e < 4; ++e) acc[c][e] += c1n0 * y0[e] + c1n1 * y1[e];
        }
    }

    // 4-wave reduce; C layout: col=lo=b-local, row=g*4+e=d
    if (wv == 1 || wv == 3) {
        float* s = red[wv >> 1];
#pragma unroll
        for (int c = 0; c < 10; ++c)
#pragma unroll
            for (int e = 0; e < 4; ++e) s[c * 256 + (g * 4 + e) * 16 + lo] = acc[c][e];
    }
    __syncthreads();
    if (wv == 0) {
#pragma unroll
        for (int c = 0; c < 10; ++c)
#pragma unroll
            for (int e = 0; e < 4; ++e) acc[c][e] += red[0][c * 256 + (g * 4 + e) * 16 + lo];
    } else if (wv == 2) {
#pragma unroll
        for (int c = 0; c < 10; ++c)
#pragma unroll
            for (int e = 0; e < 4; ++e) {
                int idx = c * 256 + (g * 4 + e) * 16 + lo;
                red[1][idx] += acc[c][e];
            }
    }
    __syncthreads();
    if (wv == 0) {
        float* dst = P + (size_t)ns * BB * CD;
#pragma unroll
        for (int c = 0; c < 10; ++c)
#pragma unroll
            for (int e = 0; e < 4; ++e)
                dst[(size_t)(btile + lo) * CD + c * 16 + g * 4 + e] =
                    acc[c][e] + red[1][c * 256 + (g * 4 + e) * 16 + lo];
    }
}

extern "C" void kernel_launch(void* const* d_in, const int* in_sizes, int n_in,
                              void* d_out, int out_size, void* d_ws, size_t ws_size,
                              hipStream_t stream)
{
    (void)in_sizes; (void)n_in; (void)out_size;
    const float* x = (const float*)d_in[0];
    const float* w = (const float*)d_in[1];
    float* out = (float*)d_out;

    char* base = (char*)d_ws;
    short* wnh = (short*)(base);
    short* wnl = (short*)(base + 2949120);
    short* wth = (short*)(base + 5898240);
    short* wtl = (short*)(base + 8847360);
    float* o0  = (float*)(base + 11796480);
    float* P   = (float*)(base + 12124160);
    const size_t fixed = 12124160, slab = (size_t)BB * CD * sizeof(float);

    p0a<<<WELEM / 256, 256, 0, stream>>>(w, wnh, wnl);
    p0b<<<WELEM / 256, 256, 0, stream>>>(w, wth, wtl);

#define LAUNCH_NS(NSV)                                                                \
    do {                                                                              \
        caps_p1<NSV><<<dim3(NSV, 32), 256, 0, stream>>>(x, wnh, wnl, P);              \
        reduce_squash<<<320, 256, 0, stream>>>(P, o0, NSV, 0.01f);                    \
        caps_p2<NSV><<<dim3(NSV, 32), 256, 0, stream>>>(x, wnh, wnl, wth, wtl, o0, P);\
        reduce_squash<<<320, 256, 0, stream>>>(P, out, NSV, 1.0f);                    \
    } while (0)

    if      (ws_size >= fixed + slab * 48) LAUNCH_NS(48);
    else if (ws_size >= fixed + slab * 24) LAUNCH_NS(24);
    else if (ws_size >= fixed + slab * 12) LAUNCH_NS(12);
    else                                   LAUNCH_NS(4);
#undef LAUNCH_NS
}